// Round 9
// baseline (283.257 us; speedup 1.0000x reference)
//
#include <hip/hip_runtime.h>

#define KNN 32
#define BLOCK 256
#define ROWS 8
#define CAP 320
#define NSLOT 128
#define T0_COEF 0.015625f  // 2*TARGET/N with TARGET=96, N=12288
#define TMIN 1e-3f
#define TMAX 8.0f

// ws (f64), per slot s at ws[s*16 + c]:
//   c=0..3: sum_y, sum_y2, sum_m, sum_m2
//   c=4: W   c=5: S1y=sum w*y_i*y_k   c=6: S2y=sum w*(y_i+y_k)   c=7: S1m   c=8: S2m
// moran num_y = S1y - mu_y*S2y + mu_y^2*W  (mean-free expansion; exact in f64)

__global__ __launch_bounds__(BLOCK, 6) void knn_moran_kernel(const float4* __restrict__ x4,
                                                             const float* __restrict__ y,
                                                             const float* __restrict__ m,
                                                             double* __restrict__ ws, int N) {
  __shared__ unsigned long long s_cand[ROWS][CAP];
  __shared__ int s_count[ROWS];
  __shared__ float s_sel_d2[ROWS][KNN];
  __shared__ int s_sel_i[ROWS][KNN];
  __shared__ double s_part[BLOCK / 64][5];
  __shared__ double s_ysum[4];

  const int i0 = blockIdx.x * ROWS;
  const int tid = threadIdx.x;
  const int lane = tid & 63;
  const int wid = tid >> 6;

  if (tid < ROWS) s_count[tid] = 0;

  // fold this block's slice of the global y/m sums (8 elements)
  if (tid < ROWS) {
    double yv = (double)y[i0 + tid], mv = (double)m[i0 + tid];
    double a = yv, b = yv * yv, c = mv, d = mv * mv;
    for (int off = 4; off > 0; off >>= 1) {
      a += __shfl_down(a, off, 8);
      b += __shfl_down(b, off, 8);
      c += __shfl_down(c, off, 8);
      d += __shfl_down(d, off, 8);
    }
    if (tid == 0) { s_ysum[0] = a; s_ysum[1] = b; s_ysum[2] = c; s_ysum[3] = d; }
  }

  // queries + analytic initial d2-threshold from the standard-normal density:
  // lambda(q) = N*exp(-|q|^2/2)/(2pi); E[count(t)] = lambda*pi*t  =>  t0 = (2*96/N)*exp(|q|^2/2)
  float qx[ROWS], qy[ROWS], qs[ROWS], tf[ROWS];
#pragma unroll
  for (int r = 0; r < ROWS; ++r) {
    float4 xi = x4[i0 + r];
    qx[r] = xi.x; qy[r] = xi.y;
    qs[r] = xi.x * xi.x + xi.y * xi.y;
    tf[r] = fminf(fmaxf(T0_COEF * __expf(0.5f * qs[r]), TMIN), TMAX);  // uniform across threads
  }
  __syncthreads();

  // ---- main pass: stream all N once, push (d2_bits, idx) for d2 < tf[r]; count is exact ----
  {
    float4 cur = x4[tid];
    const int IT = N / BLOCK;
    for (int it = 0; it < IT; ++it) {
      float4 nxt = (it + 1 < IT) ? x4[(it + 1) * BLOCK + tid] : cur;
      int j = it * BLOCK + tid;
      float sqj = cur.x * cur.x + cur.y * cur.y;
#pragma unroll
      for (int r = 0; r < ROWS; ++r) {
        float dot = qx[r] * cur.x + qy[r] * cur.y;
        float d2 = fmaxf(qs[r] + sqj - 2.0f * dot, 1e-30f);
        if (d2 < tf[r]) {
          int pos = atomicAdd(&s_count[r], 1);
          if (pos < CAP)
            s_cand[r][pos] =
                (((unsigned long long)__float_as_uint(d2)) << 32) | (unsigned long long)(unsigned)j;
        }
      }
      cur = nxt;
    }
  }

  // ---- settle loop (rare): rows with count outside [KNN, CAP] adjust threshold and rescan ----
  for (int iter = 0; iter < 16; ++iter) {
    __syncthreads();
    int mask = 0;
#pragma unroll
    for (int r = 0; r < ROWS; ++r) {
      int C = s_count[r];  // exact predicate count (increments past CAP)
      if (C < KNN) {
        mask |= 1 << r;
        tf[r] *= (C == 0) ? 8.0f : fminf(fmaxf(48.0f / (float)C, 2.0f), 16.0f);
        tf[r] = fminf(tf[r], 256.0f);  // covers max possible d2 -> guarantees termination
      } else if (C > CAP) {
        mask |= 1 << r;
        tf[r] *= 48.0f / (float)C;  // convexity of count(t): recount lands in [32, CAP]
      }
    }
    if (!mask) break;
    __syncthreads();
    if (tid < ROWS && ((mask >> tid) & 1)) s_count[tid] = 0;
    __syncthreads();
    for (int it = 0; it < N / BLOCK; ++it) {
      int j = it * BLOCK + tid;
      float4 xj = x4[j];
      float sqj = xj.x * xj.x + xj.y * xj.y;
#pragma unroll
      for (int r = 0; r < ROWS; ++r) {
        if ((mask >> r) & 1) {
          float dot = qx[r] * xj.x + qy[r] * xj.y;
          float d2 = fmaxf(qs[r] + sqj - 2.0f * dot, 1e-30f);
          if (d2 < tf[r]) {
            int pos = atomicAdd(&s_count[r], 1);
            if (pos < CAP)
              s_cand[r][pos] =
                  (((unsigned long long)__float_as_uint(d2)) << 32) | (unsigned long long)(unsigned)j;
          }
        }
      }
    }
  }
  __syncthreads();

  // ---- exact rank selection: wave wid handles rows 2*wid, 2*wid+1 (ties -> smaller idx) ----
  for (int rr = 0; rr < 2; ++rr) {
    const int r = wid * 2 + rr;
    int C = s_count[r];
    if (C > CAP) C = CAP;
    for (int c = lane; c < C; c += 64) {
      unsigned long long mine = s_cand[r][c];
      int rank = 0;
      for (int q = 0; q < C; ++q) rank += (s_cand[r][q] < mine) ? 1 : 0;
      if (rank < KNN) {
        s_sel_d2[r][rank] = __uint_as_float((unsigned)(mine >> 32));
        s_sel_i[r][rank] = (int)(unsigned)(mine & 0xffffffffull);
      }
    }
  }
  __syncthreads();

  // ---- accumulate: wave wid handles rows 2*wid, 2*wid+1; block-local partials only ----
  {
    double pW = 0.0, pS1y = 0.0, pS2y = 0.0, pS1m = 0.0, pS2m = 0.0;
    for (int rr = 0; rr < 2; ++rr) {
      const int r = wid * 2 + rr;
      const int i = i0 + r;
      float w = 0.0f, wy = 0.0f, wm = 0.0f;
      if (lane < KNN) {
        int idx = s_sel_i[r][lane];
        float dist = sqrtf(s_sel_d2[r][lane]);  // == reference sqrt(max(d2,1e-30))
        w = expf(-0.1f * dist);
        wy = w * y[idx];
        wm = w * m[idx];
      }
      for (int off = 32; off > 0; off >>= 1) {
        w  += __shfl_down(w, off, 64);
        wy += __shfl_down(wy, off, 64);
        wm += __shfl_down(wm, off, 64);
      }
      if (lane == 0) {
        double yi = (double)y[i], mi = (double)m[i];
        pW   += (double)w;
        pS1y += yi * (double)wy;
        pS2y += yi * (double)w + (double)wy;
        pS1m += mi * (double)wm;
        pS2m += mi * (double)w + (double)wm;
      }
    }
    if (lane == 0) {
      s_part[wid][0] = pW; s_part[wid][1] = pS1y; s_part[wid][2] = pS2y;
      s_part[wid][3] = pS1m; s_part[wid][4] = pS2m;
    }
  }
  __syncthreads();

  // ---- one set of 9 atomics per block into a hashed slot ----
  if (tid < 9) {
    double val;
    if (tid < 4) {
      val = s_ysum[tid];
    } else {
      val = 0.0;
      for (int w = 0; w < BLOCK / 64; ++w) val += s_part[w][tid - 4];
    }
    int base = (blockIdx.x & (NSLOT - 1)) * 16;
    atomicAdd(&ws[base + tid], val);
  }
}

__global__ __launch_bounds__(128) void finalize_kernel(const double* __restrict__ ws,
                                                       float* __restrict__ out, int N) {
  __shared__ double part[2][9];
  int tid = threadIdx.x;  // 128 threads = NSLOT
  double v[9];
#pragma unroll
  for (int c = 0; c < 9; ++c) v[c] = ws[tid * 16 + c];
#pragma unroll
  for (int c = 0; c < 9; ++c)
    for (int off = 32; off > 0; off >>= 1) v[c] += __shfl_down(v[c], off, 64);
  if ((tid & 63) == 0)
#pragma unroll
    for (int c = 0; c < 9; ++c) part[tid >> 6][c] = v[c];
  __syncthreads();
  if (tid == 0) {
    double t[9];
#pragma unroll
    for (int c = 0; c < 9; ++c) t[c] = part[0][c] + part[1][c];
    double sy = t[0], sy2 = t[1], sm = t[2], sm2 = t[3];
    double W = t[4], S1y = t[5], S2y = t[6], S1m = t[7], S2m = t[8];
    double muy = sy / (double)N, mum = sm / (double)N;
    double deny = sy2 - sy * sy / (double)N;
    double denm = sm2 - sm * sm / (double)N;
    double numy = S1y - muy * S2y + muy * muy * W;
    double numm = S1m - mum * S2m + mum * mum * W;
    out[0] = (float)((double)N / W * numy / deny);
    out[1] = (float)((double)N / W * numm / denm);
  }
}

extern "C" void kernel_launch(void* const* d_in, const int* in_sizes, int n_in,
                              void* d_out, int out_size, void* d_ws, size_t ws_size,
                              hipStream_t stream) {
  const float4* x4 = (const float4*)d_in[0];  // (1, N, 4)
  const float* y   = (const float*)d_in[1];   // (1, N, 1)
  const float* mu  = (const float*)d_in[2];   // (1, N, 1)
  float* out = (float*)d_out;
  int N = in_sizes[1];  // 12288; divisible by ROWS and BLOCK
  double* ws = (double*)d_ws;

  hipMemsetAsync(d_ws, 0, NSLOT * 16 * sizeof(double), stream);
  knn_moran_kernel<<<N / ROWS, BLOCK, 0, stream>>>(x4, y, mu, ws, N);
  finalize_kernel<<<1, 128, 0, stream>>>(ws, out, N);
}